// Round 7
// baseline (262.286 us; speedup 1.0000x reference)
//
#include <hip/hip_runtime.h>
#include <hip/hip_bf16.h>
#include <math.h>

#define BB   2
#define NPTS 16384
#define KNB  16
#define DPTS 64
#define DM   128

typedef float  f32x4  __attribute__((ext_vector_type(4)));
typedef short  bf16x8 __attribute__((ext_vector_type(8)));

__device__ __forceinline__ unsigned short f2bf(float f) {
    union { __hip_bfloat16 h; unsigned short u; } v;
    v.h = __float2bfloat16(f);
    return v.u;
}
__device__ __forceinline__ float bf2f(unsigned short h) {
    union { unsigned u; float f; } v; v.u = ((unsigned)h) << 16;
    return v.f;
}

// bf16 weight workspace layout (elems):
// DW2CAT [256][128]: rows 0..127 = dw2, rows 128..255 = W' = gw1@dw2
#define WOFF_DW2CAT 0
#define WOFF_GW2    32768   // gw2 * SCL
#define WOFF_WQP    49152   // gw1@wq
#define WOFF_WKP    65536   // gw1@wk
#define WOFF_WV     81920
#define WOFF_FC1    98304
#define WTOT        106496  // bf16 elems; f32 consts follow:
// cbuf[0..127] = c1 = gb1 + gw1@db2 ; cbuf[128..255] = gb2*SCL
#define SCL_CONST   0.12751743342f   // 1/sqrt(128) * log2(e)

// ============ Kernel 0: weight prep (products + conversions + consts) =====
__global__ __launch_bounds__(256) void prep_kernel(
    const float* __restrict__ dw2, const float* __restrict__ gw1,
    const float* __restrict__ gw2, const float* __restrict__ wq,
    const float* __restrict__ wk, const float* __restrict__ wv,
    const float* __restrict__ fc1_w, const float* __restrict__ db2,
    const float* __restrict__ gb1, const float* __restrict__ gb2,
    unsigned short* __restrict__ wb, float* __restrict__ cbuf)
{
    const int t = blockIdx.x * 256 + threadIdx.x;
    if (t < 49152) {
        // products: gw1 @ B  (B in {dw2, wq, wk}), K=128 f32 dot
        const int mat = t >> 14, off = t & 16383;
        const int r = off >> 7, k = off & 127;
        const float* Bm = (mat == 0) ? dw2 : (mat == 1) ? wq : wk;
        const float* arow = gw1 + r * DM;
        float s = 0.f;
#pragma unroll 4
        for (int u = 0; u < DM; ++u)
            s = fmaf(arow[u], Bm[u * DM + k], s);
        const int dst = (mat == 0) ? (WOFF_DW2CAT + (DM + r) * DM + k)
                      : (mat == 1) ? (WOFF_WQP + off) : (WOFF_WKP + off);
        wb[dst] = f2bf(s);
    } else if (t < 106496) {
        const int j = t - 49152;
        float v;
        int dst;
        if (j < 16384)      { v = dw2[j];  dst = WOFF_DW2CAT + j; }
        else if (j < 32768) { v = gw2[j - 16384] * SCL_CONST; dst = WOFF_GW2 + (j - 16384); }
        else if (j < 49152) { v = wv[j - 32768];  dst = WOFF_WV + (j - 32768); }
        else                { v = fc1_w[j - 49152]; dst = WOFF_FC1 + (j - 49152); }
        wb[dst] = f2bf(v);
    } else if (t < 106624) {
        const int i = t - 106496;
        const float* arow = gw1 + i * DM;
        float s = gb1[i];
#pragma unroll 4
        for (int u = 0; u < DM; ++u)
            s = fmaf(arow[u], db2[u], s);
        cbuf[i] = s;
    } else if (t < 106752) {
        const int i = t - 106624;
        cbuf[DM + i] = gb2[i] * SCL_CONST;
    }
}

// shared GEMM helper: 64x128 act tile (stride 136) vs bf16 weights [.][128],
// 32-col strip per wave
#define ABSTR 136

__device__ __forceinline__ void mfma_gemm(const unsigned short* __restrict__ AB,
                                          const unsigned short* __restrict__ Wb,
                                          int lane, int wbase, f32x4 acc[4][2])
{
    const int c = lane & 15, g = lane >> 4;
    bf16x8 Bf[2][4];
#pragma unroll
    for (int ct = 0; ct < 2; ++ct)
#pragma unroll
        for (int ks = 0; ks < 4; ++ks)
            Bf[ct][ks] = *(const bf16x8*)&Wb[(wbase + ct * 16 + c) * DM + ks * 32 + g * 8];
#pragma unroll
    for (int rt = 0; rt < 4; ++rt) {
        bf16x8 Af[4];
#pragma unroll
        for (int ks = 0; ks < 4; ++ks)
            Af[ks] = *(const bf16x8*)&AB[(rt * 16 + c) * ABSTR + ks * 32 + g * 8];
#pragma unroll
        for (int ct = 0; ct < 2; ++ct)
#pragma unroll
            for (int ks = 0; ks < 4; ++ks)
                acc[rt][ct] = __builtin_amdgcn_mfma_f32_16x16x32_bf16(
                    Af[ks], Bf[ct][ks], acc[rt][ct], 0, 0, 0);
    }
}

// ============ Kernel 1: x = fc1(features); q'/k'/v  (MFMA bf16) ===========
#define P_MT  64
#define FSTR  72

__global__ __launch_bounds__(256, 4) void proj_kernel(
    const float* __restrict__ features, const float* __restrict__ fc1_b,
    const unsigned short* __restrict__ wbf,
    unsigned short* __restrict__ qws, unsigned short* __restrict__ kws,
    unsigned short* __restrict__ vws)
{
    __shared__ __align__(16) unsigned short FB[P_MT * FSTR];
    __shared__ __align__(16) unsigned short XB[P_MT * ABSTR];

    const int tid  = threadIdx.x;
    const int lane = tid & 63;
    const int wave = tid >> 6;
    const int wbase = wave * 32;
    const int c  = lane & 15;
    const int g  = lane >> 4;
    const int g4 = g * 4;
    const size_t gp0 = (size_t)blockIdx.x * P_MT;

    for (int i = tid; i < P_MT * 8; i += 256) {
        const int r = i >> 3, o = i & 7;
        const float4 a = *(const float4*)&features[(gp0 + r) * DPTS + o * 8];
        const float4 b = *(const float4*)&features[(gp0 + r) * DPTS + o * 8 + 4];
        bf16x8 t;
        t[0] = (short)f2bf(a.x); t[1] = (short)f2bf(a.y);
        t[2] = (short)f2bf(a.z); t[3] = (short)f2bf(a.w);
        t[4] = (short)f2bf(b.x); t[5] = (short)f2bf(b.y);
        t[6] = (short)f2bf(b.z); t[7] = (short)f2bf(b.w);
        *(bf16x8*)&FB[r * FSTR + o * 8] = t;
    }
    __syncthreads();

    // GEMM0: x = features @ fc1_w.T + fc1_b  (K=64), bias-init acc
    {
        const unsigned short* fw = wbf + WOFF_FC1;
        const float b0 = fc1_b[wbase + c], b1 = fc1_b[wbase + 16 + c];
        f32x4 acc[4][2];
#pragma unroll
        for (int rt = 0; rt < 4; ++rt) {
            acc[rt][0] = (f32x4)b0;
            acc[rt][1] = (f32x4)b1;
        }
        bf16x8 Bf[2][2];
#pragma unroll
        for (int ct = 0; ct < 2; ++ct)
#pragma unroll
            for (int ks = 0; ks < 2; ++ks)
                Bf[ct][ks] = *(const bf16x8*)&fw[(wbase + ct * 16 + c) * DPTS + ks * 32 + g * 8];
#pragma unroll
        for (int rt = 0; rt < 4; ++rt) {
            bf16x8 Af[2];
#pragma unroll
            for (int ks = 0; ks < 2; ++ks)
                Af[ks] = *(const bf16x8*)&FB[(rt * 16 + c) * FSTR + ks * 32 + g * 8];
#pragma unroll
            for (int ct = 0; ct < 2; ++ct)
#pragma unroll
                for (int ks = 0; ks < 2; ++ks)
                    acc[rt][ct] = __builtin_amdgcn_mfma_f32_16x16x32_bf16(
                        Af[ks], Bf[ct][ks], acc[rt][ct], 0, 0, 0);
        }
#pragma unroll
        for (int ct = 0; ct < 2; ++ct) {
            const int col = wbase + ct * 16 + c;
#pragma unroll
            for (int rt = 0; rt < 4; ++rt)
#pragma unroll
                for (int rg = 0; rg < 4; ++rg)
                    XB[(rt * 16 + g4 + rg) * ABSTR + col] = f2bf(acc[rt][ct][rg]);
        }
    }
    __syncthreads();

    // q' = x@(gw1wq).T ; k' = x@(gw1wk).T ; v = x@wv.T
    const unsigned short* wmat[3] = { wbf + WOFF_WQP, wbf + WOFF_WKP, wbf + WOFF_WV };
    unsigned short* outp[3] = { qws, kws, vws };
#pragma unroll
    for (int m = 0; m < 3; ++m) {
        f32x4 acc[4][2];
#pragma unroll
        for (int rt = 0; rt < 4; ++rt)
#pragma unroll
            for (int ct = 0; ct < 2; ++ct) acc[rt][ct] = (f32x4)0.f;
        mfma_gemm(XB, wmat[m], lane, wbase, acc);
#pragma unroll
        for (int ct = 0; ct < 2; ++ct) {
            const int col = wbase + ct * 16 + c;
#pragma unroll
            for (int rt = 0; rt < 4; ++rt)
#pragma unroll
                for (int rg = 0; rg < 4; ++rg)
                    outp[m][(gp0 + rt * 16 + g4 + rg) * DM + col] = f2bf(acc[rt][ct][rg]);
        }
    }
}

// ============ Kernel 2: fused neighbor pipeline (2 GEMM phases) ===========
#define K2_PTS 4
#define K2_R   (K2_PTS * KNB)   // 64 rows

__global__ __launch_bounds__(256, 4) void attn_kernel(
    const float* __restrict__ new_xyz, const float* __restrict__ grouped_xyz,
    const int* __restrict__ grouped_idx,
    const float* __restrict__ dw1, const float* __restrict__ db1,
    const float* __restrict__ db2,
    const unsigned short* __restrict__ wbf, const float* __restrict__ cbuf,
    const unsigned short* __restrict__ qws, const unsigned short* __restrict__ kws,
    const unsigned short* __restrict__ vws,
    float* __restrict__ out)
{
    __shared__ __align__(16) unsigned short AB[K2_R * ABSTR];  // relu1, then g1
    __shared__ __align__(16) unsigned short SB[K2_R * ABSTR];  // posW
    __shared__ float REL[K2_R * 3];
    __shared__ int   IDX[K2_R];

    const int tid  = threadIdx.x;
    const int lane = tid & 63;
    const int wave = tid >> 6;
    const int wbase = wave * 32;
    const int c  = lane & 15;
    const int g  = lane >> 4;
    const int g4 = g * 4;
    const int rr = tid >> 4;
    const int o8 = (tid & 15) * 8;

    const int b   = blockIdx.x / (NPTS / K2_PTS);
    const int m0  = (blockIdx.x % (NPTS / K2_PTS)) * K2_PTS;
    const size_t gp0 = (size_t)b * NPTS + m0;
    const size_t bN  = (size_t)b * NPTS;

    const unsigned short* dw2c0 = wbf + WOFF_DW2CAT;            // rows 0..127: dw2
    const unsigned short* dw2c1 = wbf + WOFF_DW2CAT + DM * DM;  // rows 128..255: W'
    const unsigned short* gw2b  = wbf + WOFF_GW2;               // gw2*SCL

    // hoist dw1/db1 rows for this thread's col octet
    float wr[24], bbv[8];
    {
        const float4* wsrc = (const float4*)&dw1[o8 * 3];
#pragma unroll
        for (int t = 0; t < 6; ++t) ((float4*)wr)[t] = wsrc[t];
        const float4* bsrc = (const float4*)&db1[o8];
        ((float4*)bbv)[0] = bsrc[0];
        ((float4*)bbv)[1] = bsrc[1];
    }

    // ---- P0: idx + rel ----
    if (tid < K2_R) {
        const int p = tid >> 4, j = tid & 15;
        const size_t m = gp0 + p;
        const int mi = m0 + p;
        IDX[tid] = grouped_idx[m * KNB + j];
#pragma unroll
        for (int cc = 0; cc < 3; ++cc)
            REL[tid * 3 + cc] = new_xyz[m * 3 + cc]
                              - grouped_xyz[(((size_t)b * 3 + cc) * NPTS + mi) * KNB + j];
    }
    __syncthreads();

    // prefetch q'/k' gathers (T14: issue-early; consumed in P3)
    bf16x8 q8[4], k8[4];
#pragma unroll
    for (int it = 0; it < 4; ++it) {
        const int r = it * 16 + rr;
        q8[it] = *(const bf16x8*)&qws[(gp0 + it) * DM + o8];
        k8[it] = *(const bf16x8*)&kws[(bN + IDX[r]) * DM + o8];
    }

    // ---- P1: relu1 = relu(rel @ dw1.T + db1) -> AB ----
#pragma unroll
    for (int it = 0; it < 4; ++it) {
        const int r = it * 16 + rr;
        const float rx = REL[r * 3 + 0], ry = REL[r * 3 + 1], rz = REL[r * 3 + 2];
        bf16x8 t;
#pragma unroll
        for (int j = 0; j < 8; ++j) {
            float v = bbv[j];
            v = fmaf(rx, wr[j * 3 + 0], v);
            v = fmaf(ry, wr[j * 3 + 1], v);
            v = fmaf(rz, wr[j * 3 + 2], v);
            t[j] = (short)f2bf(fmaxf(v, 0.f));
        }
        *(bf16x8*)&AB[r * ABSTR + o8] = t;
    }
    __syncthreads();

    // ---- P2a: posW = relu1@W'.T + c1 -> SB (pw dies immediately) ----
    {
        const float c10 = cbuf[wbase + c], c11 = cbuf[wbase + 16 + c];
        f32x4 pw[4][2];
#pragma unroll
        for (int rt = 0; rt < 4; ++rt) {
            pw[rt][0] = (f32x4)c10;
            pw[rt][1] = (f32x4)c11;
        }
        mfma_gemm(AB, dw2c1, lane, wbase, pw);
#pragma unroll
        for (int ct = 0; ct < 2; ++ct) {
            const int col = wbase + ct * 16 + c;
#pragma unroll
            for (int rt = 0; rt < 4; ++rt)
#pragma unroll
                for (int rg = 0; rg < 4; ++rg)
                    SB[(rt * 16 + g4 + rg) * ABSTR + col] = f2bf(pw[rt][ct][rg]);
        }
    }

    // ---- P2b: pos = relu1@dw2.T + db2 (stays in regs through P5) ----
    f32x4 posr[4][2];
    {
        const float b0 = db2[wbase + c], b1 = db2[wbase + 16 + c];
#pragma unroll
        for (int rt = 0; rt < 4; ++rt) {
            posr[rt][0] = (f32x4)b0;
            posr[rt][1] = (f32x4)b1;
        }
    }
    mfma_gemm(AB, dw2c0, lane, wbase, posr);
    __syncthreads();   // SB visible; all AB reads done

    // ---- P3: g1 = relu(q' - k' + posW) -> AB ----
#pragma unroll
    for (int it = 0; it < 4; ++it) {
        const int r = it * 16 + rr;
        const bf16x8 p8 = *(const bf16x8*)&SB[r * ABSTR + o8];
        bf16x8 t;
#pragma unroll
        for (int j = 0; j < 8; ++j) {
            const float hv = bf2f((unsigned short)q8[it][j])
                           - bf2f((unsigned short)k8[it][j])
                           + bf2f((unsigned short)p8[j]);
            t[j] = (short)f2bf(fmaxf(hv, 0.f));
        }
        *(bf16x8*)&AB[r * ABSTR + o8] = t;
    }
    __syncthreads();

    // ---- P4: logits2 = g1 @ (gw2*SCL).T + gb2*SCL (regs; zero epilogue) ----
    f32x4 lg[4][2];
    {
        const float s0 = cbuf[DM + wbase + c], s1 = cbuf[DM + wbase + 16 + c];
#pragma unroll
        for (int rt = 0; rt < 4; ++rt) {
            lg[rt][0] = (f32x4)s0;
            lg[rt][1] = (f32x4)s1;
        }
    }
    mfma_gemm(AB, gw2b, lane, wbase, lg);

    // ---- P5: softmax over 16 neighbors + output reduce ----
#pragma unroll
    for (int rt = 0; rt < 4; ++rt)
#pragma unroll
    for (int ct = 0; ct < 2; ++ct) {
        const int col = wbase + ct * 16 + c;
        f32x4 l = lg[rt][ct];
        float mx = fmaxf(fmaxf(l[0], l[1]), fmaxf(l[2], l[3]));
        mx = fmaxf(mx, __shfl_xor(mx, 16));
        mx = fmaxf(mx, __shfl_xor(mx, 32));
        f32x4 e;
        e[0] = __builtin_amdgcn_exp2f(l[0] - mx);
        e[1] = __builtin_amdgcn_exp2f(l[1] - mx);
        e[2] = __builtin_amdgcn_exp2f(l[2] - mx);
        e[3] = __builtin_amdgcn_exp2f(l[3] - mx);
        float s = e[0] + e[1] + e[2] + e[3];
        s += __shfl_xor(s, 16);
        s += __shfl_xor(s, 32);
        float o = 0.f;
#pragma unroll
        for (int rg = 0; rg < 4; ++rg) {
            const int row = rt * 16 + g4 + rg;
            const float vv = bf2f(vws[(bN + IDX[row]) * DM + col]) + posr[rt][ct][rg];
            o = fmaf(e[rg], vv, o);
        }
        o += __shfl_xor(o, 16);
        o += __shfl_xor(o, 32);
        if (g == 0)
            out[(gp0 + rt) * DM + col] = o * __builtin_amdgcn_rcpf(s);
    }
}

// ======================= launch =======================
extern "C" void kernel_launch(void* const* d_in, const int* in_sizes, int n_in,
                              void* d_out, int out_size, void* d_ws, size_t ws_size,
                              hipStream_t stream)
{
    const float* new_xyz     = (const float*)d_in[0];
    const float* grouped_xyz = (const float*)d_in[1];
    const int*   grouped_idx = (const int*)d_in[2];
    const float* features    = (const float*)d_in[3];
    const float* fc1_w = (const float*)d_in[4];
    const float* fc1_b = (const float*)d_in[5];
    const float* wq    = (const float*)d_in[6];
    const float* wk    = (const float*)d_in[7];
    const float* wv    = (const float*)d_in[8];
    const float* dw1   = (const float*)d_in[9];
    const float* db1   = (const float*)d_in[10];
    const float* dw2   = (const float*)d_in[11];
    const float* db2   = (const float*)d_in[12];
    const float* gw1   = (const float*)d_in[13];
    const float* gb1   = (const float*)d_in[14];
    const float* gw2   = (const float*)d_in[15];
    const float* gb2   = (const float*)d_in[16];
    float* out = (float*)d_out;

    unsigned short* ws = (unsigned short*)d_ws;
    const size_t npt = (size_t)BB * NPTS * DM;
    unsigned short* qws = ws;          // q' = gw1·q
    unsigned short* kws = ws + npt;    // k' = gw1·k
    unsigned short* vws = ws + 2 * npt;
    unsigned short* wbf = ws + 3 * npt;
    float* cbuf = (float*)(wbf + WTOT);

    prep_kernel<<<(106752 + 255) / 256, 256, 0, stream>>>(
        dw2, gw1, gw2, wq, wk, wv, fc1_w, db2, gb1, gb2, wbf, cbuf);

    proj_kernel<<<(BB * NPTS) / P_MT, 256, 0, stream>>>(
        features, fc1_b, wbf, qws, kws, vws);

    attn_kernel<<<(BB * NPTS) / K2_PTS, 256, 0, stream>>>(
        new_xyz, grouped_xyz, grouped_idx,
        dw1, db1, db2,
        wbf, cbuf, qws, kws, vws, out);
}

// Round 8
// 201.939 us; speedup vs baseline: 1.2988x; 1.2988x over previous
//
#include <hip/hip_runtime.h>
#include <hip/hip_bf16.h>
#include <math.h>

#define BB   2
#define NPTS 16384
#define KNB  16
#define DPTS 64
#define DM   128

typedef float  f32x4  __attribute__((ext_vector_type(4)));
typedef short  bf16x8 __attribute__((ext_vector_type(8)));

__device__ __forceinline__ unsigned short f2bf(float f) {
    union { __hip_bfloat16 h; unsigned short u; } v;
    v.h = __float2bfloat16(f);
    return v.u;
}
__device__ __forceinline__ float bf2f(unsigned short h) {
    union { unsigned u; float f; } v; v.u = ((unsigned)h) << 16;
    return v.f;
}

// bf16 weight workspace layout (elems):
// DW2CAT [256][128]: rows 0..127 = dw2, rows 128..255 = W' = gw1@dw2
#define WOFF_DW2CAT 0
#define WOFF_GW2    32768   // gw2 * SCL
#define WOFF_WQP    49152   // gw1@wq
#define WOFF_WKP    65536   // gw1@wk
#define WOFF_WV     81920
#define WOFF_FC1    98304
#define WTOT        106496  // bf16 elems; f32 consts follow:
// cbuf[0..127] = c1 = gb1 + gw1@db2 ; cbuf[128..255] = gb2*SCL
#define SCL_CONST   0.12751743342f   // 1/sqrt(128) * log2(e)

// ============ Kernel 0: weight prep (products + conversions + consts) =====
__global__ __launch_bounds__(256) void prep_kernel(
    const float* __restrict__ dw2, const float* __restrict__ gw1,
    const float* __restrict__ gw2, const float* __restrict__ wq,
    const float* __restrict__ wk, const float* __restrict__ wv,
    const float* __restrict__ fc1_w, const float* __restrict__ db2,
    const float* __restrict__ gb1, const float* __restrict__ gb2,
    unsigned short* __restrict__ wb, float* __restrict__ cbuf)
{
    const int t = blockIdx.x * 256 + threadIdx.x;
    if (t < 49152) {
        // products: gw1 @ B  (B in {dw2, wq, wk}), K=128 f32 dot
        const int mat = t >> 14, off = t & 16383;
        const int r = off >> 7, k = off & 127;
        const float* Bm = (mat == 0) ? dw2 : (mat == 1) ? wq : wk;
        const float* arow = gw1 + r * DM;
        float s = 0.f;
#pragma unroll 4
        for (int u = 0; u < DM; ++u)
            s = fmaf(arow[u], Bm[u * DM + k], s);
        const int dst = (mat == 0) ? (WOFF_DW2CAT + (DM + r) * DM + k)
                      : (mat == 1) ? (WOFF_WQP + off) : (WOFF_WKP + off);
        wb[dst] = f2bf(s);
    } else if (t < 106496) {
        const int j = t - 49152;
        float v;
        int dst;
        if (j < 16384)      { v = dw2[j];  dst = WOFF_DW2CAT + j; }
        else if (j < 32768) { v = gw2[j - 16384] * SCL_CONST; dst = WOFF_GW2 + (j - 16384); }
        else if (j < 49152) { v = wv[j - 32768];  dst = WOFF_WV + (j - 32768); }
        else                { v = fc1_w[j - 49152]; dst = WOFF_FC1 + (j - 49152); }
        wb[dst] = f2bf(v);
    } else if (t < 106624) {
        const int i = t - 106496;
        const float* arow = gw1 + i * DM;
        float s = gb1[i];
#pragma unroll 4
        for (int u = 0; u < DM; ++u)
            s = fmaf(arow[u], db2[u], s);
        cbuf[i] = s;
    } else if (t < 106752) {
        const int i = t - 106624;
        cbuf[DM + i] = gb2[i] * SCL_CONST;
    }
}

// shared GEMM helper: 64x128 act tile (stride 136) vs bf16 weights [.][128],
// 32-col strip per wave
#define ABSTR 136

__device__ __forceinline__ void mfma_gemm(const unsigned short* __restrict__ AB,
                                          const unsigned short* __restrict__ Wb,
                                          int lane, int wbase, f32x4 acc[4][2])
{
    const int c = lane & 15, g = lane >> 4;
    bf16x8 Bf[2][4];
#pragma unroll
    for (int ct = 0; ct < 2; ++ct)
#pragma unroll
        for (int ks = 0; ks < 4; ++ks)
            Bf[ct][ks] = *(const bf16x8*)&Wb[(wbase + ct * 16 + c) * DM + ks * 32 + g * 8];
#pragma unroll
    for (int rt = 0; rt < 4; ++rt) {
        bf16x8 Af[4];
#pragma unroll
        for (int ks = 0; ks < 4; ++ks)
            Af[ks] = *(const bf16x8*)&AB[(rt * 16 + c) * ABSTR + ks * 32 + g * 8];
#pragma unroll
        for (int ct = 0; ct < 2; ++ct)
#pragma unroll
            for (int ks = 0; ks < 4; ++ks)
                acc[rt][ct] = __builtin_amdgcn_mfma_f32_16x16x32_bf16(
                    Af[ks], Bf[ct][ks], acc[rt][ct], 0, 0, 0);
    }
}

// ============ Kernel 1: x = fc1(features); q'/k'/v  (MFMA bf16) ===========
#define P_MT  64
#define FSTR  72

__global__ __launch_bounds__(256, 4) void proj_kernel(
    const float* __restrict__ features, const float* __restrict__ fc1_b,
    const unsigned short* __restrict__ wbf,
    unsigned short* __restrict__ qws, unsigned short* __restrict__ kws,
    unsigned short* __restrict__ vws)
{
    __shared__ __align__(16) unsigned short FB[P_MT * FSTR];
    __shared__ __align__(16) unsigned short XB[P_MT * ABSTR];

    const int tid  = threadIdx.x;
    const int lane = tid & 63;
    const int wave = tid >> 6;
    const int wbase = wave * 32;
    const int c  = lane & 15;
    const int g  = lane >> 4;
    const int g4 = g * 4;
    const size_t gp0 = (size_t)blockIdx.x * P_MT;

    for (int i = tid; i < P_MT * 8; i += 256) {
        const int r = i >> 3, o = i & 7;
        const float4 a = *(const float4*)&features[(gp0 + r) * DPTS + o * 8];
        const float4 b = *(const float4*)&features[(gp0 + r) * DPTS + o * 8 + 4];
        bf16x8 t;
        t[0] = (short)f2bf(a.x); t[1] = (short)f2bf(a.y);
        t[2] = (short)f2bf(a.z); t[3] = (short)f2bf(a.w);
        t[4] = (short)f2bf(b.x); t[5] = (short)f2bf(b.y);
        t[6] = (short)f2bf(b.z); t[7] = (short)f2bf(b.w);
        *(bf16x8*)&FB[r * FSTR + o * 8] = t;
    }
    __syncthreads();

    // GEMM0: x = features @ fc1_w.T + fc1_b  (K=64), bias-init acc
    {
        const unsigned short* fw = wbf + WOFF_FC1;
        const float b0 = fc1_b[wbase + c], b1 = fc1_b[wbase + 16 + c];
        f32x4 acc[4][2];
#pragma unroll
        for (int rt = 0; rt < 4; ++rt) {
            acc[rt][0] = (f32x4)b0;
            acc[rt][1] = (f32x4)b1;
        }
        bf16x8 Bf[2][2];
#pragma unroll
        for (int ct = 0; ct < 2; ++ct)
#pragma unroll
            for (int ks = 0; ks < 2; ++ks)
                Bf[ct][ks] = *(const bf16x8*)&fw[(wbase + ct * 16 + c) * DPTS + ks * 32 + g * 8];
#pragma unroll
        for (int rt = 0; rt < 4; ++rt) {
            bf16x8 Af[2];
#pragma unroll
            for (int ks = 0; ks < 2; ++ks)
                Af[ks] = *(const bf16x8*)&FB[(rt * 16 + c) * FSTR + ks * 32 + g * 8];
#pragma unroll
            for (int ct = 0; ct < 2; ++ct)
#pragma unroll
                for (int ks = 0; ks < 2; ++ks)
                    acc[rt][ct] = __builtin_amdgcn_mfma_f32_16x16x32_bf16(
                        Af[ks], Bf[ct][ks], acc[rt][ct], 0, 0, 0);
        }
#pragma unroll
        for (int ct = 0; ct < 2; ++ct) {
            const int col = wbase + ct * 16 + c;
#pragma unroll
            for (int rt = 0; rt < 4; ++rt)
#pragma unroll
                for (int rg = 0; rg < 4; ++rg)
                    XB[(rt * 16 + g4 + rg) * ABSTR + col] = f2bf(acc[rt][ct][rg]);
        }
    }
    __syncthreads();

    // q' = x@(gw1wq).T ; k' = x@(gw1wk).T ; v = x@wv.T
    const unsigned short* wmat[3] = { wbf + WOFF_WQP, wbf + WOFF_WKP, wbf + WOFF_WV };
    unsigned short* outp[3] = { qws, kws, vws };
#pragma unroll
    for (int m = 0; m < 3; ++m) {
        f32x4 acc[4][2];
#pragma unroll
        for (int rt = 0; rt < 4; ++rt)
#pragma unroll
            for (int ct = 0; ct < 2; ++ct) acc[rt][ct] = (f32x4)0.f;
        mfma_gemm(XB, wmat[m], lane, wbase, acc);
#pragma unroll
        for (int ct = 0; ct < 2; ++ct) {
            const int col = wbase + ct * 16 + c;
#pragma unroll
            for (int rt = 0; rt < 4; ++rt)
#pragma unroll
                for (int rg = 0; rg < 4; ++rg)
                    outp[m][(gp0 + rt * 16 + g4 + rg) * DM + col] = f2bf(acc[rt][ct][rg]);
        }
    }
}

// ============ Kernel 2: fused neighbor pipeline (2 GEMM phases) ===========
// __launch_bounds__(256, 3): the algebraic version's peak live set
// (pw+posr AGPRs + q8/k8 + wr/bbv + frags ~ 150 regs) exceeds the 128-reg
// cap of (256,4) -> r6/r7 spilled 188-508 MB to scratch. 3 waves/EU gives
// ~170 regs; LDS still allows 4 blocks/CU but regs cap us at 3 (12 waves).
#define K2_PTS 4
#define K2_R   (K2_PTS * KNB)   // 64 rows

__global__ __launch_bounds__(256, 3) void attn_kernel(
    const float* __restrict__ new_xyz, const float* __restrict__ grouped_xyz,
    const int* __restrict__ grouped_idx,
    const float* __restrict__ dw1, const float* __restrict__ db1,
    const float* __restrict__ db2,
    const unsigned short* __restrict__ wbf, const float* __restrict__ cbuf,
    const unsigned short* __restrict__ qws, const unsigned short* __restrict__ kws,
    const unsigned short* __restrict__ vws,
    float* __restrict__ out)
{
    __shared__ __align__(16) unsigned short AB[K2_R * ABSTR];  // relu1, then g1
    __shared__ __align__(16) unsigned short SB[K2_R * ABSTR];  // posW
    __shared__ float REL[K2_R * 3];
    __shared__ int   IDX[K2_R];

    const int tid  = threadIdx.x;
    const int lane = tid & 63;
    const int wave = tid >> 6;
    const int wbase = wave * 32;
    const int c  = lane & 15;
    const int g  = lane >> 4;
    const int g4 = g * 4;
    const int rr = tid >> 4;
    const int o8 = (tid & 15) * 8;

    const int b   = blockIdx.x / (NPTS / K2_PTS);
    const int m0  = (blockIdx.x % (NPTS / K2_PTS)) * K2_PTS;
    const size_t gp0 = (size_t)b * NPTS + m0;
    const size_t bN  = (size_t)b * NPTS;

    const unsigned short* dw2c0 = wbf + WOFF_DW2CAT;            // rows 0..127: dw2
    const unsigned short* dw2c1 = wbf + WOFF_DW2CAT + DM * DM;  // rows 128..255: W'
    const unsigned short* gw2b  = wbf + WOFF_GW2;               // gw2*SCL

    // hoist dw1/db1 rows for this thread's col octet
    float wr[24], bbv[8];
    {
        const float4* wsrc = (const float4*)&dw1[o8 * 3];
#pragma unroll
        for (int t = 0; t < 6; ++t) ((float4*)wr)[t] = wsrc[t];
        const float4* bsrc = (const float4*)&db1[o8];
        ((float4*)bbv)[0] = bsrc[0];
        ((float4*)bbv)[1] = bsrc[1];
    }

    // ---- P0: idx + rel ----
    if (tid < K2_R) {
        const int p = tid >> 4, j = tid & 15;
        const size_t m = gp0 + p;
        const int mi = m0 + p;
        IDX[tid] = grouped_idx[m * KNB + j];
#pragma unroll
        for (int cc = 0; cc < 3; ++cc)
            REL[tid * 3 + cc] = new_xyz[m * 3 + cc]
                              - grouped_xyz[(((size_t)b * 3 + cc) * NPTS + mi) * KNB + j];
    }
    __syncthreads();

    // prefetch q'/k' gathers (T14: issue-early; consumed in P3)
    bf16x8 q8[4], k8[4];
#pragma unroll
    for (int it = 0; it < 4; ++it) {
        const int r = it * 16 + rr;
        q8[it] = *(const bf16x8*)&qws[(gp0 + it) * DM + o8];
        k8[it] = *(const bf16x8*)&kws[(bN + IDX[r]) * DM + o8];
    }

    // ---- P1: relu1 = relu(rel @ dw1.T + db1) -> AB ----
#pragma unroll
    for (int it = 0; it < 4; ++it) {
        const int r = it * 16 + rr;
        const float rx = REL[r * 3 + 0], ry = REL[r * 3 + 1], rz = REL[r * 3 + 2];
        bf16x8 t;
#pragma unroll
        for (int j = 0; j < 8; ++j) {
            float v = bbv[j];
            v = fmaf(rx, wr[j * 3 + 0], v);
            v = fmaf(ry, wr[j * 3 + 1], v);
            v = fmaf(rz, wr[j * 3 + 2], v);
            t[j] = (short)f2bf(fmaxf(v, 0.f));
        }
        *(bf16x8*)&AB[r * ABSTR + o8] = t;
    }
    __syncthreads();

    // ---- P2a: posW = relu1@W'.T + c1 -> SB ----
    {
        const float c10 = cbuf[wbase + c], c11 = cbuf[wbase + 16 + c];
        f32x4 pw[4][2];
#pragma unroll
        for (int rt = 0; rt < 4; ++rt) {
            pw[rt][0] = (f32x4)c10;
            pw[rt][1] = (f32x4)c11;
        }
        mfma_gemm(AB, dw2c1, lane, wbase, pw);
#pragma unroll
        for (int ct = 0; ct < 2; ++ct) {
            const int col = wbase + ct * 16 + c;
#pragma unroll
            for (int rt = 0; rt < 4; ++rt)
#pragma unroll
                for (int rg = 0; rg < 4; ++rg)
                    SB[(rt * 16 + g4 + rg) * ABSTR + col] = f2bf(pw[rt][ct][rg]);
        }
    }

    // ---- P2b: pos = relu1@dw2.T + db2 (stays in regs through P5) ----
    f32x4 posr[4][2];
    {
        const float b0 = db2[wbase + c], b1 = db2[wbase + 16 + c];
#pragma unroll
        for (int rt = 0; rt < 4; ++rt) {
            posr[rt][0] = (f32x4)b0;
            posr[rt][1] = (f32x4)b1;
        }
    }
    mfma_gemm(AB, dw2c0, lane, wbase, posr);
    __syncthreads();   // SB visible; all AB reads done

    // ---- P3: g1 = relu(q' - k' + posW) -> AB ----
#pragma unroll
    for (int it = 0; it < 4; ++it) {
        const int r = it * 16 + rr;
        const bf16x8 p8 = *(const bf16x8*)&SB[r * ABSTR + o8];
        bf16x8 t;
#pragma unroll
        for (int j = 0; j < 8; ++j) {
            const float hv = bf2f((unsigned short)q8[it][j])
                           - bf2f((unsigned short)k8[it][j])
                           + bf2f((unsigned short)p8[j]);
            t[j] = (short)f2bf(fmaxf(hv, 0.f));
        }
        *(bf16x8*)&AB[r * ABSTR + o8] = t;
    }
    __syncthreads();

    // ---- P4: logits2 = g1 @ (gw2*SCL).T + gb2*SCL (regs; zero epilogue) ----
    f32x4 lg[4][2];
    {
        const float s0 = cbuf[DM + wbase + c], s1 = cbuf[DM + wbase + 16 + c];
#pragma unroll
        for (int rt = 0; rt < 4; ++rt) {
            lg[rt][0] = (f32x4)s0;
            lg[rt][1] = (f32x4)s1;
        }
    }
    mfma_gemm(AB, gw2b, lane, wbase, lg);

    // ---- P5: softmax over 16 neighbors + output reduce ----
#pragma unroll
    for (int rt = 0; rt < 4; ++rt)
#pragma unroll
    for (int ct = 0; ct < 2; ++ct) {
        const int col = wbase + ct * 16 + c;
        f32x4 l = lg[rt][ct];
        float mx = fmaxf(fmaxf(l[0], l[1]), fmaxf(l[2], l[3]));
        mx = fmaxf(mx, __shfl_xor(mx, 16));
        mx = fmaxf(mx, __shfl_xor(mx, 32));
        f32x4 e;
        e[0] = __builtin_amdgcn_exp2f(l[0] - mx);
        e[1] = __builtin_amdgcn_exp2f(l[1] - mx);
        e[2] = __builtin_amdgcn_exp2f(l[2] - mx);
        e[3] = __builtin_amdgcn_exp2f(l[3] - mx);
        float s = e[0] + e[1] + e[2] + e[3];
        s += __shfl_xor(s, 16);
        s += __shfl_xor(s, 32);
        float o = 0.f;
#pragma unroll
        for (int rg = 0; rg < 4; ++rg) {
            const int row = rt * 16 + g4 + rg;
            const float vv = bf2f(vws[(bN + IDX[row]) * DM + col]) + posr[rt][ct][rg];
            o = fmaf(e[rg], vv, o);
        }
        o += __shfl_xor(o, 16);
        o += __shfl_xor(o, 32);
        if (g == 0)
            out[(gp0 + rt) * DM + col] = o * __builtin_amdgcn_rcpf(s);
    }
}

// ======================= launch =======================
extern "C" void kernel_launch(void* const* d_in, const int* in_sizes, int n_in,
                              void* d_out, int out_size, void* d_ws, size_t ws_size,
                              hipStream_t stream)
{
    const float* new_xyz     = (const float*)d_in[0];
    const float* grouped_xyz = (const float*)d_in[1];
    const int*   grouped_idx = (const int*)d_in[2];
    const float* features    = (const float*)d_in[3];
    const float* fc1_w = (const float*)d_in[4];
    const float* fc1_b = (const float*)d_in[5];
    const float* wq    = (const float*)d_in[6];
    const float* wk    = (const float*)d_in[7];
    const float* wv    = (const float*)d_in[8];
    const float* dw1   = (const float*)d_in[9];
    const float* db1   = (const float*)d_in[10];
    const float* dw2   = (const float*)d_in[11];
    const float* db2   = (const float*)d_in[12];
    const float* gw1   = (const float*)d_in[13];
    const float* gb1   = (const float*)d_in[14];
    const float* gw2   = (const float*)d_in[15];
    const float* gb2   = (const float*)d_in[16];
    float* out = (float*)d_out;

    unsigned short* ws = (unsigned short*)d_ws;
    const size_t npt = (size_t)BB * NPTS * DM;
    unsigned short* qws = ws;          // q' = gw1·q
    unsigned short* kws = ws + npt;    // k' = gw1·k
    unsigned short* vws = ws + 2 * npt;
    unsigned short* wbf = ws + 3 * npt;
    float* cbuf = (float*)(wbf + WTOT);

    prep_kernel<<<(106752 + 255) / 256, 256, 0, stream>>>(
        dw2, gw1, gw2, wq, wk, wv, fc1_w, db2, gb1, gb2, wbf, cbuf);

    proj_kernel<<<(BB * NPTS) / P_MT, 256, 0, stream>>>(
        features, fc1_b, wbf, qws, kws, vws);

    attn_kernel<<<(BB * NPTS) / K2_PTS, 256, 0, stream>>>(
        new_xyz, grouped_xyz, grouped_idx,
        dw1, db1, db2,
        wbf, cbuf, qws, kws, vws, out);
}

// Round 9
// 183.274 us; speedup vs baseline: 1.4311x; 1.1018x over previous
//
#include <hip/hip_runtime.h>
#include <hip/hip_bf16.h>
#include <math.h>

#define BB   2
#define NPTS 16384
#define KNB  16
#define DPTS 64
#define DM   128

typedef float  f32x4  __attribute__((ext_vector_type(4)));
typedef short  bf16x8 __attribute__((ext_vector_type(8)));

__device__ __forceinline__ unsigned short f2bf(float f) {
    union { __hip_bfloat16 h; unsigned short u; } v;
    v.h = __float2bfloat16(f);
    return v.u;
}
__device__ __forceinline__ float bf2f(unsigned short h) {
    union { unsigned u; float f; } v; v.u = ((unsigned)h) << 16;
    return v.f;
}

// bf16 weight workspace layout (elems):
// DW2CAT [256][128]: rows 0..127 = dw2, rows 128..255 = W' = gw1@dw2
#define WOFF_DW2CAT 0
#define WOFF_GW2    32768   // gw2 * SCL
#define WOFF_WQP    49152   // gw1@wq
#define WOFF_WKP    65536   // gw1@wk
#define WOFF_WV     81920
#define WOFF_FC1    98304
#define WTOT        106496  // bf16 elems; f32 consts follow:
// cbuf[0..127] = c1 = gb1 + gw1@db2 ; cbuf[128..255] = gb2*SCL
#define SCL_CONST   0.12751743342f   // 1/sqrt(128) * log2(e)

// ============ Kernel 0: weight prep (products + conversions + consts) =====
__global__ __launch_bounds__(256) void prep_kernel(
    const float* __restrict__ dw2, const float* __restrict__ gw1,
    const float* __restrict__ gw2, const float* __restrict__ wq,
    const float* __restrict__ wk, const float* __restrict__ wv,
    const float* __restrict__ fc1_w, const float* __restrict__ db2,
    const float* __restrict__ gb1, const float* __restrict__ gb2,
    unsigned short* __restrict__ wb, float* __restrict__ cbuf)
{
    const int t = blockIdx.x * 256 + threadIdx.x;
    if (t < 49152) {
        // products: gw1 @ B  (B in {dw2, wq, wk}), K=128 f32 dot
        const int mat = t >> 14, off = t & 16383;
        const int r = off >> 7, k = off & 127;
        const float* Bm = (mat == 0) ? dw2 : (mat == 1) ? wq : wk;
        const float* arow = gw1 + r * DM;
        float s = 0.f;
#pragma unroll 4
        for (int u = 0; u < DM; ++u)
            s = fmaf(arow[u], Bm[u * DM + k], s);
        const int dst = (mat == 0) ? (WOFF_DW2CAT + (DM + r) * DM + k)
                      : (mat == 1) ? (WOFF_WQP + off) : (WOFF_WKP + off);
        wb[dst] = f2bf(s);
    } else if (t < 106496) {
        const int j = t - 49152;
        float v;
        int dst;
        if (j < 16384)      { v = dw2[j];  dst = WOFF_DW2CAT + j; }
        else if (j < 32768) { v = gw2[j - 16384] * SCL_CONST; dst = WOFF_GW2 + (j - 16384); }
        else if (j < 49152) { v = wv[j - 32768];  dst = WOFF_WV + (j - 32768); }
        else                { v = fc1_w[j - 49152]; dst = WOFF_FC1 + (j - 49152); }
        wb[dst] = f2bf(v);
    } else if (t < 106624) {
        const int i = t - 106496;
        const float* arow = gw1 + i * DM;
        float s = gb1[i];
#pragma unroll 4
        for (int u = 0; u < DM; ++u)
            s = fmaf(arow[u], db2[u], s);
        cbuf[i] = s;
    } else if (t < 106752) {
        const int i = t - 106624;
        cbuf[DM + i] = gb2[i] * SCL_CONST;
    }
}

#define ABSTR 136

// 32-col-strip GEMM (256-thread proj kernel)
__device__ __forceinline__ void mfma_gemm(const unsigned short* __restrict__ AB,
                                          const unsigned short* __restrict__ Wb,
                                          int lane, int wbase, f32x4 acc[4][2])
{
    const int c = lane & 15, g = lane >> 4;
    bf16x8 Bf[2][4];
#pragma unroll
    for (int ct = 0; ct < 2; ++ct)
#pragma unroll
        for (int ks = 0; ks < 4; ++ks)
            Bf[ct][ks] = *(const bf16x8*)&Wb[(wbase + ct * 16 + c) * DM + ks * 32 + g * 8];
#pragma unroll
    for (int rt = 0; rt < 4; ++rt) {
        bf16x8 Af[4];
#pragma unroll
        for (int ks = 0; ks < 4; ++ks)
            Af[ks] = *(const bf16x8*)&AB[(rt * 16 + c) * ABSTR + ks * 32 + g * 8];
#pragma unroll
        for (int ct = 0; ct < 2; ++ct)
#pragma unroll
            for (int ks = 0; ks < 4; ++ks)
                acc[rt][ct] = __builtin_amdgcn_mfma_f32_16x16x32_bf16(
                    Af[ks], Bf[ct][ks], acc[rt][ct], 0, 0, 0);
    }
}

// 16-col-strip GEMM (512-thread attn kernel): one col per lane-c, 4 row tiles
__device__ __forceinline__ void gemm16(const unsigned short* __restrict__ X,
                                       const unsigned short* __restrict__ Wb,
                                       int c, int g, int wb16, f32x4 acc[4])
{
    bf16x8 Bf[4];
#pragma unroll
    for (int ks = 0; ks < 4; ++ks)
        Bf[ks] = *(const bf16x8*)&Wb[(wb16 + c) * DM + ks * 32 + g * 8];
#pragma unroll
    for (int rt = 0; rt < 4; ++rt) {
        bf16x8 Af[4];
#pragma unroll
        for (int ks = 0; ks < 4; ++ks)
            Af[ks] = *(const bf16x8*)&X[(rt * 16 + c) * ABSTR + ks * 32 + g * 8];
#pragma unroll
        for (int ks = 0; ks < 4; ++ks)
            acc[rt] = __builtin_amdgcn_mfma_f32_16x16x32_bf16(
                Af[ks], Bf[ks], acc[rt], 0, 0, 0);
    }
}

// ============ Kernel 1: x = fc1(features); q'/k'/v  (MFMA bf16) ===========
#define P_MT  64
#define FSTR  72

__global__ __launch_bounds__(256, 4) void proj_kernel(
    const float* __restrict__ features, const float* __restrict__ fc1_b,
    const unsigned short* __restrict__ wbf,
    unsigned short* __restrict__ qws, unsigned short* __restrict__ kws,
    unsigned short* __restrict__ vws)
{
    __shared__ __align__(16) unsigned short FB[P_MT * FSTR];
    __shared__ __align__(16) unsigned short XB[P_MT * ABSTR];

    const int tid  = threadIdx.x;
    const int lane = tid & 63;
    const int wave = tid >> 6;
    const int wbase = wave * 32;
    const int c  = lane & 15;
    const int g  = lane >> 4;
    const int g4 = g * 4;
    const size_t gp0 = (size_t)blockIdx.x * P_MT;

    for (int i = tid; i < P_MT * 8; i += 256) {
        const int r = i >> 3, o = i & 7;
        const float4 a = *(const float4*)&features[(gp0 + r) * DPTS + o * 8];
        const float4 b = *(const float4*)&features[(gp0 + r) * DPTS + o * 8 + 4];
        bf16x8 t;
        t[0] = (short)f2bf(a.x); t[1] = (short)f2bf(a.y);
        t[2] = (short)f2bf(a.z); t[3] = (short)f2bf(a.w);
        t[4] = (short)f2bf(b.x); t[5] = (short)f2bf(b.y);
        t[6] = (short)f2bf(b.z); t[7] = (short)f2bf(b.w);
        *(bf16x8*)&FB[r * FSTR + o * 8] = t;
    }
    __syncthreads();

    // GEMM0: x = features @ fc1_w.T + fc1_b  (K=64), bias-init acc
    {
        const unsigned short* fw = wbf + WOFF_FC1;
        const float b0 = fc1_b[wbase + c], b1 = fc1_b[wbase + 16 + c];
        f32x4 acc[4][2];
#pragma unroll
        for (int rt = 0; rt < 4; ++rt) {
            acc[rt][0] = (f32x4)b0;
            acc[rt][1] = (f32x4)b1;
        }
        bf16x8 Bf[2][2];
#pragma unroll
        for (int ct = 0; ct < 2; ++ct)
#pragma unroll
            for (int ks = 0; ks < 2; ++ks)
                Bf[ct][ks] = *(const bf16x8*)&fw[(wbase + ct * 16 + c) * DPTS + ks * 32 + g * 8];
#pragma unroll
        for (int rt = 0; rt < 4; ++rt) {
            bf16x8 Af[2];
#pragma unroll
            for (int ks = 0; ks < 2; ++ks)
                Af[ks] = *(const bf16x8*)&FB[(rt * 16 + c) * FSTR + ks * 32 + g * 8];
#pragma unroll
            for (int ct = 0; ct < 2; ++ct)
#pragma unroll
                for (int ks = 0; ks < 2; ++ks)
                    acc[rt][ct] = __builtin_amdgcn_mfma_f32_16x16x32_bf16(
                        Af[ks], Bf[ct][ks], acc[rt][ct], 0, 0, 0);
        }
#pragma unroll
        for (int ct = 0; ct < 2; ++ct) {
            const int col = wbase + ct * 16 + c;
#pragma unroll
            for (int rt = 0; rt < 4; ++rt)
#pragma unroll
                for (int rg = 0; rg < 4; ++rg)
                    XB[(rt * 16 + g4 + rg) * ABSTR + col] = f2bf(acc[rt][ct][rg]);
        }
    }
    __syncthreads();

    // q' = x@(gw1wq).T ; k' = x@(gw1wk).T ; v = x@wv.T
    const unsigned short* wmat[3] = { wbf + WOFF_WQP, wbf + WOFF_WKP, wbf + WOFF_WV };
    unsigned short* outp[3] = { qws, kws, vws };
#pragma unroll
    for (int m = 0; m < 3; ++m) {
        f32x4 acc[4][2];
#pragma unroll
        for (int rt = 0; rt < 4; ++rt)
#pragma unroll
            for (int ct = 0; ct < 2; ++ct) acc[rt][ct] = (f32x4)0.f;
        mfma_gemm(XB, wmat[m], lane, wbase, acc);
#pragma unroll
        for (int ct = 0; ct < 2; ++ct) {
            const int col = wbase + ct * 16 + c;
#pragma unroll
            for (int rt = 0; rt < 4; ++rt)
#pragma unroll
                for (int rg = 0; rg < 4; ++rg)
                    outp[m][(gp0 + rt * 16 + g4 + rg) * DM + col] = f2bf(acc[rt][ct][rg]);
        }
    }
}

// ============ Kernel 2: fused neighbor pipeline ===========================
// 512 threads, 8 waves x 16-col strips; SINGLE in-place LDS buffer (~19.5KB)
// -> 3 blocks/CU (24 waves, 75% occ) at the (512,6) 85-reg cap.
#define K2_PTS 4
#define K2_R   (K2_PTS * KNB)   // 64 rows

__global__ __launch_bounds__(512, 6) void attn_kernel(
    const float* __restrict__ new_xyz, const float* __restrict__ grouped_xyz,
    const int* __restrict__ grouped_idx,
    const float* __restrict__ dw1, const float* __restrict__ db1,
    const float* __restrict__ db2,
    const unsigned short* __restrict__ wbf, const float* __restrict__ cbuf,
    const unsigned short* __restrict__ qws, const unsigned short* __restrict__ kws,
    const unsigned short* __restrict__ vws,
    float* __restrict__ out)
{
    __shared__ __align__(16) unsigned short X[K2_R * ABSTR];   // 17408 B
    __shared__ __align__(16) unsigned short QB[K2_PTS * DM];   //  1024 B
    __shared__ float REL[K2_R * 3];
    __shared__ int   IDX[K2_R];

    const int tid  = threadIdx.x;
    const int lane = tid & 63;
    const int wave = tid >> 6;         // 0..7
    const int wb16 = wave * 16;        // 16-col strip base
    const int c  = lane & 15;
    const int g  = lane >> 4;
    const int g4 = g * 4;
    const int r0e = tid >> 4;          // elementwise row A (0..31); row B = +32
    const int o8  = (tid & 15) * 8;    // col octet base

    const int b   = blockIdx.x / (NPTS / K2_PTS);
    const int m0  = (blockIdx.x % (NPTS / K2_PTS)) * K2_PTS;
    const size_t gp0 = (size_t)b * NPTS + m0;
    const size_t bN  = (size_t)b * NPTS;

    const unsigned short* dw2c0 = wbf + WOFF_DW2CAT;            // dw2
    const unsigned short* dw2c1 = wbf + WOFF_DW2CAT + DM * DM;  // W' = gw1@dw2
    const unsigned short* gw2b  = wbf + WOFF_GW2;               // gw2*SCL

    // ---- P0: idx + rel (waves 0-3's first 64 threads) ; stage q' (wave 7) --
    if (tid < K2_R) {
        const int p = tid >> 4, j = tid & 15;
        const size_t m = gp0 + p;
        const int mi = m0 + p;
        IDX[tid] = grouped_idx[m * KNB + j];
#pragma unroll
        for (int cc = 0; cc < 3; ++cc)
            REL[tid * 3 + cc] = new_xyz[m * 3 + cc]
                              - grouped_xyz[(((size_t)b * 3 + cc) * NPTS + mi) * KNB + j];
    } else if (tid >= 448) {
        const int i = tid - 448;               // 64 octets = 4 rows x 16
        const int r = i >> 4, o = (i & 15) * 8;
        *(bf16x8*)&QB[r * DM + o] = *(const bf16x8*)&qws[(gp0 + r) * DM + o];
    }
    __syncthreads();

    // ---- P1: relu1 = relu(rel @ dw1.T + db1) -> X (2 octets/thread) ----
    {
        float wr[24], bbv[8];
        const float4* wsrc = (const float4*)&dw1[o8 * 3];
#pragma unroll
        for (int t = 0; t < 6; ++t) ((float4*)wr)[t] = wsrc[t];
        const float4* bsrc = (const float4*)&db1[o8];
        ((float4*)bbv)[0] = bsrc[0];
        ((float4*)bbv)[1] = bsrc[1];
#pragma unroll
        for (int half = 0; half < 2; ++half) {
            const int r = r0e + half * 32;
            const float rx = REL[r * 3 + 0], ry = REL[r * 3 + 1], rz = REL[r * 3 + 2];
            bf16x8 t;
#pragma unroll
            for (int j = 0; j < 8; ++j) {
                float v = bbv[j];
                v = fmaf(rx, wr[j * 3 + 0], v);
                v = fmaf(ry, wr[j * 3 + 1], v);
                v = fmaf(rz, wr[j * 3 + 2], v);
                t[j] = (short)f2bf(fmaxf(v, 0.f));
            }
            *(bf16x8*)&X[r * ABSTR + o8] = t;
        }
    }
    __syncthreads();

    // ---- P2: posW = relu1@W'.T + c1 ; pos = relu1@dw2.T + db2 (both read X)
    f32x4 pw[4];
    {
        const float c1v = cbuf[wb16 + c];
#pragma unroll
        for (int rt = 0; rt < 4; ++rt) pw[rt] = (f32x4)c1v;
    }
    gemm16(X, dw2c1, c, g, wb16, pw);

    f32x4 posr[4];
    {
        const float b2v = db2[wb16 + c];
#pragma unroll
        for (int rt = 0; rt < 4; ++rt) posr[rt] = (f32x4)b2v;
    }
    gemm16(X, dw2c0, c, g, wb16, posr);

    // prefetch k' gathers here (short live range; lands during write+barrier)
    bf16x8 k8a = *(const bf16x8*)&kws[(bN + IDX[r0e]) * DM + o8];
    bf16x8 k8b = *(const bf16x8*)&kws[(bN + IDX[r0e + 32]) * DM + o8];

    __syncthreads();   // ALL relu1 reads complete -> X may be overwritten

    // write posW -> X (in place, D-frag layout)
#pragma unroll
    for (int rt = 0; rt < 4; ++rt)
#pragma unroll
        for (int rg = 0; rg < 4; ++rg)
            X[(rt * 16 + g4 + rg) * ABSTR + wb16 + c] = f2bf(pw[rt][rg]);
    __syncthreads();

    // ---- P3: g1 = relu(q' - k' + posW) -> X (in place, same octet) ----
#pragma unroll
    for (int half = 0; half < 2; ++half) {
        const int r = r0e + half * 32;
        const bf16x8 p8 = *(const bf16x8*)&X[r * ABSTR + o8];
        const bf16x8 q8 = *(const bf16x8*)&QB[(r >> 4) * DM + o8];
        const bf16x8 k8 = half ? k8b : k8a;
        bf16x8 t;
#pragma unroll
        for (int j = 0; j < 8; ++j) {
            const float hv = bf2f((unsigned short)q8[j])
                           - bf2f((unsigned short)k8[j])
                           + bf2f((unsigned short)p8[j]);
            t[j] = (short)f2bf(fmaxf(hv, 0.f));
        }
        *(bf16x8*)&X[r * ABSTR + o8] = t;
    }
    __syncthreads();

    // ---- P4: logits = g1 @ (gw2*SCL).T + gb2*SCL (regs; no LDS write) ----
    f32x4 lg[4];
    {
        const float s0 = cbuf[DM + wb16 + c];
#pragma unroll
        for (int rt = 0; rt < 4; ++rt) lg[rt] = (f32x4)s0;
    }
    gemm16(X, gw2b, c, g, wb16, lg);

    // ---- P5: softmax over 16 neighbors + output reduce ----
#pragma unroll
    for (int rt = 0; rt < 4; ++rt) {
        const int col = wb16 + c;
        f32x4 l = lg[rt];
        float mx = fmaxf(fmaxf(l[0], l[1]), fmaxf(l[2], l[3]));
        mx = fmaxf(mx, __shfl_xor(mx, 16));
        mx = fmaxf(mx, __shfl_xor(mx, 32));
        f32x4 e;
        e[0] = __builtin_amdgcn_exp2f(l[0] - mx);
        e[1] = __builtin_amdgcn_exp2f(l[1] - mx);
        e[2] = __builtin_amdgcn_exp2f(l[2] - mx);
        e[3] = __builtin_amdgcn_exp2f(l[3] - mx);
        float s = e[0] + e[1] + e[2] + e[3];
        s += __shfl_xor(s, 16);
        s += __shfl_xor(s, 32);
        float o = 0.f;
#pragma unroll
        for (int rg = 0; rg < 4; ++rg) {
            const int row = rt * 16 + g4 + rg;
            const float vv = bf2f(vws[(bN + IDX[row]) * DM + col]) + posr[rt][rg];
            o = fmaf(e[rg], vv, o);
        }
        o += __shfl_xor(o, 16);
        o += __shfl_xor(o, 32);
        if (g == 0)
            out[(gp0 + rt) * DM + col] = o * __builtin_amdgcn_rcpf(s);
    }
}

// ======================= launch =======================
extern "C" void kernel_launch(void* const* d_in, const int* in_sizes, int n_in,
                              void* d_out, int out_size, void* d_ws, size_t ws_size,
                              hipStream_t stream)
{
    const float* new_xyz     = (const float*)d_in[0];
    const float* grouped_xyz = (const float*)d_in[1];
    const int*   grouped_idx = (const int*)d_in[2];
    const float* features    = (const float*)d_in[3];
    const float* fc1_w = (const float*)d_in[4];
    const float* fc1_b = (const float*)d_in[5];
    const float* wq    = (const float*)d_in[6];
    const float* wk    = (const float*)d_in[7];
    const float* wv    = (const float*)d_in[8];
    const float* dw1   = (const float*)d_in[9];
    const float* db1   = (const float*)d_in[10];
    const float* dw2   = (const float*)d_in[11];
    const float* db2   = (const float*)d_in[12];
    const float* gw1   = (const float*)d_in[13];
    const float* gb1   = (const float*)d_in[14];
    const float* gw2   = (const float*)d_in[15];
    const float* gb2   = (const float*)d_in[16];
    float* out = (float*)d_out;

    unsigned short* ws = (unsigned short*)d_ws;
    const size_t npt = (size_t)BB * NPTS * DM;
    unsigned short* qws = ws;          // q' = gw1·q
    unsigned short* kws = ws + npt;    // k' = gw1·k
    unsigned short* vws = ws + 2 * npt;
    unsigned short* wbf = ws + 3 * npt;
    float* cbuf = (float*)(wbf + WTOT);

    prep_kernel<<<(106752 + 255) / 256, 256, 0, stream>>>(
        dw2, gw1, gw2, wq, wk, wv, fc1_w, db2, gb1, gb2, wbf, cbuf);

    proj_kernel<<<(BB * NPTS) / P_MT, 256, 0, stream>>>(
        features, fc1_b, wbf, qws, kws, vws);

    attn_kernel<<<(BB * NPTS) / K2_PTS, 512, 0, stream>>>(
        new_xyz, grouped_xyz, grouped_idx,
        dw1, db1, db2,
        wbf, cbuf, qws, kws, vws, out);
}

// Round 10
// 163.032 us; speedup vs baseline: 1.6088x; 1.1242x over previous
//
#include <hip/hip_runtime.h>
#include <hip/hip_bf16.h>
#include <math.h>

#define BB   2
#define NPTS 16384
#define KNB  16
#define DPTS 64
#define DM   128

typedef float  f32x4  __attribute__((ext_vector_type(4)));
typedef short  bf16x8 __attribute__((ext_vector_type(8)));

__device__ __forceinline__ unsigned short f2bf(float f) {
    union { __hip_bfloat16 h; unsigned short u; } v;
    v.h = __float2bfloat16(f);
    return v.u;
}
__device__ __forceinline__ float bf2f(unsigned short h) {
    union { unsigned u; float f; } v; v.u = ((unsigned)h) << 16;
    return v.f;
}

// LDS tile: 64 rows x 128 bf16, XOR-swizzled (T2/G4).
// short-index = row*128 + (col ^ ((row&7)<<3)); XOR hits bits>=3 so any
// 8-short (16B) aligned vector stays contiguous, and GEMM A-frag reads go
// 8-way -> 2-way bank conflict (free per m136).
__device__ __forceinline__ int swz(int row, int col) {
    return row * DM + (col ^ ((row & 7) << 3));
}

// wbf layout (bf16 elems): [dw2 16K | gw1 16K | gw2 16K | wq 16K | wk 16K | wv 16K | fc1_w 8K]
#define WOFF_DW2  0
#define WOFF_GW1  16384
#define WOFF_GW2  32768
#define WOFF_WQ   49152
#define WOFF_WK   65536
#define WOFF_WV   81920
#define WOFF_FC1  98304
#define WTOT      106496

// ============ Kernel 0: one-shot weight conversion f32 -> bf16 ============
__global__ __launch_bounds__(256) void cvtw_kernel(
    const float* __restrict__ dw2, const float* __restrict__ gw1,
    const float* __restrict__ gw2, const float* __restrict__ wq,
    const float* __restrict__ wk, const float* __restrict__ wv,
    const float* __restrict__ fc1_w, unsigned short* __restrict__ wb)
{
    const int i = blockIdx.x * 256 + threadIdx.x;
    if (i >= WTOT) return;
    float v;
    if (i < WOFF_WQ) {
        const int which = i >> 14, off = i & 16383;
        v = (which == 0) ? dw2[off] : (which == 1) ? gw1[off] : gw2[off];
    } else if (i < WOFF_FC1) {
        const int j = i - WOFF_WQ;
        const int which = j >> 14, off = j & 16383;
        v = (which == 0) ? wq[off] : (which == 1) ? wk[off] : wv[off];
    } else {
        v = fc1_w[i - WOFF_FC1];
    }
    wb[i] = f2bf(v);
}

// shared GEMM helper: 64x128 swizzled act tile vs bf16 weights [128][128],
// 32-col strip per wave
__device__ __forceinline__ void mfma_gemm(const unsigned short* __restrict__ AB,
                                          const unsigned short* __restrict__ Wb,
                                          int lane, int wbase, f32x4 acc[4][2])
{
    const int c = lane & 15, g = lane >> 4;
    bf16x8 Bf[2][4];
#pragma unroll
    for (int ct = 0; ct < 2; ++ct)
#pragma unroll
        for (int ks = 0; ks < 4; ++ks)
            Bf[ct][ks] = *(const bf16x8*)&Wb[(wbase + ct * 16 + c) * DM + ks * 32 + g * 8];
#pragma unroll
    for (int rt = 0; rt < 4; ++rt) {
        bf16x8 Af[4];
#pragma unroll
        for (int ks = 0; ks < 4; ++ks)
            Af[ks] = *(const bf16x8*)&AB[swz(rt * 16 + c, ks * 32 + g * 8)];
#pragma unroll
        for (int ct = 0; ct < 2; ++ct)
#pragma unroll
            for (int ks = 0; ks < 4; ++ks)
                acc[rt][ct] = __builtin_amdgcn_mfma_f32_16x16x32_bf16(
                    Af[ks], Bf[ct][ks], acc[rt][ct], 0, 0, 0);
    }
}

// ============ Kernel 1: x = fc1(features); q/k/v  (MFMA bf16) =============
#define P_MT  64
#define FSTR  72

__global__ __launch_bounds__(256, 4) void proj_kernel(
    const float* __restrict__ features, const float* __restrict__ fc1_b,
    const unsigned short* __restrict__ wbf,
    unsigned short* __restrict__ qws, unsigned short* __restrict__ kws,
    unsigned short* __restrict__ vws)
{
    __shared__ __align__(16) unsigned short FB[P_MT * FSTR];   //  9216 B
    __shared__ __align__(16) unsigned short XB[P_MT * DM];     // 16384 B (swizzled)

    const int tid  = threadIdx.x;
    const int lane = tid & 63;
    const int wave = tid >> 6;
    const int wbase = wave * 32;
    const int c  = lane & 15;
    const int g  = lane >> 4;
    const int g4 = g * 4;
    const size_t gp0 = (size_t)blockIdx.x * P_MT;

    for (int i = tid; i < P_MT * 8; i += 256) {
        const int r = i >> 3, o = i & 7;
        const float4 a = *(const float4*)&features[(gp0 + r) * DPTS + o * 8];
        const float4 b = *(const float4*)&features[(gp0 + r) * DPTS + o * 8 + 4];
        bf16x8 t;
        t[0] = (short)f2bf(a.x); t[1] = (short)f2bf(a.y);
        t[2] = (short)f2bf(a.z); t[3] = (short)f2bf(a.w);
        t[4] = (short)f2bf(b.x); t[5] = (short)f2bf(b.y);
        t[6] = (short)f2bf(b.z); t[7] = (short)f2bf(b.w);
        *(bf16x8*)&FB[r * FSTR + o * 8] = t;
    }
    __syncthreads();

    // GEMM0: x = features @ fc1_w.T + fc1_b  (K=64)
    {
        const unsigned short* fw = wbf + WOFF_FC1;
        const float b0 = fc1_b[wbase + c], b1 = fc1_b[wbase + 16 + c];
        f32x4 acc[4][2];
#pragma unroll
        for (int rt = 0; rt < 4; ++rt) {
            acc[rt][0] = (f32x4)b0;
            acc[rt][1] = (f32x4)b1;
        }
        bf16x8 Bf[2][2];
#pragma unroll
        for (int ct = 0; ct < 2; ++ct)
#pragma unroll
            for (int ks = 0; ks < 2; ++ks)
                Bf[ct][ks] = *(const bf16x8*)&fw[(wbase + ct * 16 + c) * DPTS + ks * 32 + g * 8];
#pragma unroll
        for (int rt = 0; rt < 4; ++rt) {
            bf16x8 Af[2];
#pragma unroll
            for (int ks = 0; ks < 2; ++ks)
                Af[ks] = *(const bf16x8*)&FB[(rt * 16 + c) * FSTR + ks * 32 + g * 8];
#pragma unroll
            for (int ct = 0; ct < 2; ++ct)
#pragma unroll
                for (int ks = 0; ks < 2; ++ks)
                    acc[rt][ct] = __builtin_amdgcn_mfma_f32_16x16x32_bf16(
                        Af[ks], Bf[ct][ks], acc[rt][ct], 0, 0, 0);
        }
#pragma unroll
        for (int ct = 0; ct < 2; ++ct) {
            const int col = wbase + ct * 16 + c;
#pragma unroll
            for (int rt = 0; rt < 4; ++rt)
#pragma unroll
                for (int rg = 0; rg < 4; ++rg)
                    XB[swz(rt * 16 + g4 + rg, col)] = f2bf(acc[rt][ct][rg]);
        }
    }
    __syncthreads();

    // q = x@wq.T ; k = x@wk.T ; v = x@wv.T
    const unsigned short* wmat[3] = { wbf + WOFF_WQ, wbf + WOFF_WK, wbf + WOFF_WV };
    unsigned short* outp[3] = { qws, kws, vws };
#pragma unroll
    for (int m = 0; m < 3; ++m) {
        f32x4 acc[4][2];
#pragma unroll
        for (int rt = 0; rt < 4; ++rt)
#pragma unroll
            for (int ct = 0; ct < 2; ++ct) acc[rt][ct] = (f32x4)0.f;
        mfma_gemm(XB, wmat[m], lane, wbase, acc);
#pragma unroll
        for (int ct = 0; ct < 2; ++ct) {
            const int col = wbase + ct * 16 + c;
#pragma unroll
            for (int rt = 0; rt < 4; ++rt)
#pragma unroll
                for (int rg = 0; rg < 4; ++rg)
                    outp[m][(gp0 + rt * 16 + g4 + rg) * DM + col] = f2bf(acc[rt][ct][rg]);
        }
    }
}

// ============ Kernel 2: fused neighbor pipeline (MFMA bf16, swizzled) =====
#define K2_PTS 4
#define K2_R   (K2_PTS * KNB)   // 64 rows

__global__ __launch_bounds__(256, 4) void attn_kernel(
    const float* __restrict__ new_xyz, const float* __restrict__ grouped_xyz,
    const int* __restrict__ grouped_idx,
    const float* __restrict__ dw1, const float* __restrict__ db1,
    const float* __restrict__ db2,
    const float* __restrict__ gb1, const float* __restrict__ gb2,
    const unsigned short* __restrict__ wbf,
    const unsigned short* __restrict__ qws, const unsigned short* __restrict__ kws,
    const unsigned short* __restrict__ vws,
    float* __restrict__ out)
{
    __shared__ __align__(16) unsigned short AB[K2_R * DM];  // 16384 B
    __shared__ __align__(16) unsigned short SB[K2_R * DM];  // 16384 B (pos, then g1)
    __shared__ float REL[K2_R * 3];
    __shared__ int   IDX[K2_R];

    const int tid  = threadIdx.x;
    const int lane = tid & 63;
    const int wave = tid >> 6;
    const int wbase = wave * 32;
    const int c  = lane & 15;
    const int g  = lane >> 4;
    const int g4 = g * 4;
    const int rr = tid >> 4;        // row-within-group for vector phases
    const int o8 = (tid & 15) * 8;  // col octet base

    const int b   = blockIdx.x / (NPTS / K2_PTS);
    const int m0  = (blockIdx.x % (NPTS / K2_PTS)) * K2_PTS;
    const size_t gp0 = (size_t)b * NPTS + m0;
    const size_t bN  = (size_t)b * NPTS;
    // 1/sqrt(128) * log2(e): use exp2 for softmax
    const float SCL = 0.12751743342f;

    const unsigned short* dw2b = wbf + WOFF_DW2;
    const unsigned short* gw1b = wbf + WOFF_GW1;
    const unsigned short* gw2b = wbf + WOFF_GW2;

    // hoist dw1/db1 rows for this thread's col octet (fixed across iters)
    float wr[24], bbv[8];
    {
        const float4* wsrc = (const float4*)&dw1[o8 * 3];
#pragma unroll
        for (int t = 0; t < 6; ++t) ((float4*)wr)[t] = wsrc[t];
        const float4* bsrc = (const float4*)&db1[o8];
        ((float4*)bbv)[0] = bsrc[0];
        ((float4*)bbv)[1] = bsrc[1];
    }

    // ---- P0: idx + rel ----
    if (tid < K2_R) {
        const int p = tid >> 4, j = tid & 15;
        const size_t m = gp0 + p;
        const int mi = m0 + p;
        IDX[tid] = grouped_idx[m * KNB + j];
#pragma unroll
        for (int cc = 0; cc < 3; ++cc)
            REL[tid * 3 + cc] = new_xyz[m * 3 + cc]
                              - grouped_xyz[(((size_t)b * 3 + cc) * NPTS + mi) * KNB + j];
    }
    __syncthreads();

    // ---- prefetch q/k gathers (T14: issue-early, consume in P3) ----
    bf16x8 q8[4], k8[4];
#pragma unroll
    for (int it = 0; it < 4; ++it) {
        const int r = it * 16 + rr;
        q8[it] = *(const bf16x8*)&qws[(gp0 + it) * DM + o8];
        k8[it] = *(const bf16x8*)&kws[(bN + IDX[r]) * DM + o8];
    }

    // ---- P1: inner1 = relu(rel @ dw1.T + db1) -> AB (bf16, swizzled) ----
#pragma unroll
    for (int it = 0; it < 4; ++it) {
        const int r = it * 16 + rr;
        const float rx = REL[r * 3 + 0], ry = REL[r * 3 + 1], rz = REL[r * 3 + 2];
        bf16x8 t;
#pragma unroll
        for (int j = 0; j < 8; ++j) {
            float v = bbv[j];
            v = fmaf(rx, wr[j * 3 + 0], v);
            v = fmaf(ry, wr[j * 3 + 1], v);
            v = fmaf(rz, wr[j * 3 + 2], v);
            t[j] = (short)f2bf(fmaxf(v, 0.f));
        }
        *(bf16x8*)&AB[swz(r, o8)] = t;
    }
    __syncthreads();

    // ---- P2: GEMM1 pos = inner1 @ dw2.T + db2 ; f32 in regs, bf16 -> SB ----
    f32x4 posr[4][2];
    {
        const float b0 = db2[wbase + c], b1 = db2[wbase + 16 + c];
#pragma unroll
        for (int rt = 0; rt < 4; ++rt) {
            posr[rt][0] = (f32x4)b0;
            posr[rt][1] = (f32x4)b1;
        }
        mfma_gemm(AB, dw2b, lane, wbase, posr);
#pragma unroll
        for (int ct = 0; ct < 2; ++ct) {
            const int col = wbase + ct * 16 + c;
#pragma unroll
            for (int rt = 0; rt < 4; ++rt)
#pragma unroll
                for (int rg = 0; rg < 4; ++rg)
                    SB[swz(rt * 16 + g4 + rg, col)] = f2bf(posr[rt][ct][rg]);
        }
    }
    __syncthreads();

    // ---- P3: h = q - k_gather + pos -> AB (bf16, prefetched q/k) ----
#pragma unroll
    for (int it = 0; it < 4; ++it) {
        const int r = it * 16 + rr;
        const bf16x8 p8 = *(const bf16x8*)&SB[swz(r, o8)];
        bf16x8 t;
#pragma unroll
        for (int j = 0; j < 8; ++j) {
            const float hv = bf2f((unsigned short)q8[it][j])
                           - bf2f((unsigned short)k8[it][j])
                           + bf2f((unsigned short)p8[j]);
            t[j] = (short)f2bf(hv);
        }
        *(bf16x8*)&AB[swz(r, o8)] = t;
    }
    __syncthreads();

    // ---- P4: GEMM2 g1 = relu(h @ gw1.T + gb1) -> SB (pos dead; no mid-barrier)
    {
        f32x4 acc[4][2];
        const float b0 = gb1[wbase + c], b1 = gb1[wbase + 16 + c];
#pragma unroll
        for (int rt = 0; rt < 4; ++rt) {
            acc[rt][0] = (f32x4)b0;
            acc[rt][1] = (f32x4)b1;
        }
        mfma_gemm(AB, gw1b, lane, wbase, acc);
#pragma unroll
        for (int ct = 0; ct < 2; ++ct) {
            const int col = wbase + ct * 16 + c;
#pragma unroll
            for (int rt = 0; rt < 4; ++rt)
#pragma unroll
                for (int rg = 0; rg < 4; ++rg)
                    SB[swz(rt * 16 + g4 + rg, col)] = f2bf(fmaxf(acc[rt][ct][rg], 0.f));
        }
    }
    __syncthreads();

    // ---- P5: GEMM3 logits = (g1 @ gw2.T + gb2) * scl (regs) ----
    f32x4 lg[4][2];
#pragma unroll
    for (int rt = 0; rt < 4; ++rt)
#pragma unroll
        for (int ct = 0; ct < 2; ++ct) lg[rt][ct] = (f32x4)0.f;
    mfma_gemm(SB, gw2b, lane, wbase, lg);
#pragma unroll
    for (int ct = 0; ct < 2; ++ct) {
        const int col = wbase + ct * 16 + c;
        const float bb = gb2[col];
#pragma unroll
        for (int rt = 0; rt < 4; ++rt)
#pragma unroll
            for (int rg = 0; rg < 4; ++rg)
                lg[rt][ct][rg] = (lg[rt][ct][rg] + bb) * SCL;
    }

    // ---- P6: in-register softmax over 16 neighbors + output reduce ----
    // D layout: col = wbase+ct*16+c, row-in-tile = g*4+rg; rowtile == point.
#pragma unroll
    for (int rt = 0; rt < 4; ++rt)
#pragma unroll
    for (int ct = 0; ct < 2; ++ct) {
        const int col = wbase + ct * 16 + c;
        f32x4 l = lg[rt][ct];
        float mx = fmaxf(fmaxf(l[0], l[1]), fmaxf(l[2], l[3]));
        mx = fmaxf(mx, __shfl_xor(mx, 16));
        mx = fmaxf(mx, __shfl_xor(mx, 32));
        f32x4 e;
        e[0] = __builtin_amdgcn_exp2f(l[0] - mx);
        e[1] = __builtin_amdgcn_exp2f(l[1] - mx);
        e[2] = __builtin_amdgcn_exp2f(l[2] - mx);
        e[3] = __builtin_amdgcn_exp2f(l[3] - mx);
        float s = e[0] + e[1] + e[2] + e[3];
        s += __shfl_xor(s, 16);
        s += __shfl_xor(s, 32);
        float o = 0.f;
#pragma unroll
        for (int rg = 0; rg < 4; ++rg) {
            const int row = rt * 16 + g4 + rg;
            const float vv = bf2f(vws[(bN + IDX[row]) * DM + col]) + posr[rt][ct][rg];
            o = fmaf(e[rg], vv, o);
        }
        o += __shfl_xor(o, 16);
        o += __shfl_xor(o, 32);
        if (g == 0)
            out[(gp0 + rt) * DM + col] = o * __builtin_amdgcn_rcpf(s);
    }
}

// ======================= launch =======================
extern "C" void kernel_launch(void* const* d_in, const int* in_sizes, int n_in,
                              void* d_out, int out_size, void* d_ws, size_t ws_size,
                              hipStream_t stream)
{
    const float* new_xyz     = (const float*)d_in[0];
    const float* grouped_xyz = (const float*)d_in[1];
    const int*   grouped_idx = (const int*)d_in[2];
    const float* features    = (const float*)d_in[3];
    const float* fc1_w = (const float*)d_in[4];
    const float* fc1_b = (const float*)d_in[5];
    const float* wq    = (const float*)d_in[6];
    const float* wk    = (const float*)d_in[7];
    const float* wv    = (const float*)d_in[8];
    const float* dw1   = (const float*)d_in[9];
    const float* db1   = (const float*)d_in[10];
    const float* dw2   = (const float*)d_in[11];
    const float* db2   = (const float*)d_in[12];
    const float* gw1   = (const float*)d_in[13];
    const float* gb1   = (const float*)d_in[14];
    const float* gw2   = (const float*)d_in[15];
    const float* gb2   = (const float*)d_in[16];
    float* out = (float*)d_out;

    unsigned short* ws = (unsigned short*)d_ws;
    const size_t npt = (size_t)BB * NPTS * DM;
    unsigned short* qws = ws;
    unsigned short* kws = ws + npt;
    unsigned short* vws = ws + 2 * npt;
    unsigned short* wbf = ws + 3 * npt;

    cvtw_kernel<<<(WTOT + 255) / 256, 256, 0, stream>>>(
        dw2, gw1, gw2, wq, wk, wv, fc1_w, wbf);

    proj_kernel<<<(BB * NPTS) / P_MT, 256, 0, stream>>>(
        features, fc1_b, wbf, qws, kws, vws);

    attn_kernel<<<(BB * NPTS) / K2_PTS, 256, 0, stream>>>(
        new_xyz, grouped_xyz, grouped_idx,
        dw1, db1, db2, gb1, gb2,
        wbf, qws, kws, vws, out);
}